// Round 1
// baseline (569.460 us; speedup 1.0000x reference)
//
#include <hip/hip_runtime.h>

// Problem constants (CausalMultiHeadSelfAttention): B=4, S=2048, E=1024, H=16, D=64
#define E_DIM 1024
#define N_HEADS 16
#define HEAD_D 64
#define BATCH 4
#define SEQ 2048
#define M_ROWS (BATCH * SEQ)  // 8192

typedef __attribute__((ext_vector_type(4))) float f32x4;
typedef __attribute__((ext_vector_type(8))) short s16x8;  // 8 bf16 in 4 VGPRs

__device__ __forceinline__ unsigned short f2b(float f) {
  union { float f; unsigned u; } v; v.f = f;
  unsigned r = v.u + 0x7fffu + ((v.u >> 16) & 1u);  // RNE
  return (unsigned short)(r >> 16);
}

__device__ __forceinline__ void gld16(const void* g, void* l) {
  __builtin_amdgcn_global_load_lds(
      (__attribute__((address_space(1))) void*)(g),
      (__attribute__((address_space(3))) void*)(l), 16, 0, 0);
}

// ---------------- cast x (fp32 -> bf16), vectorized ----------------
__global__ __launch_bounds__(256) void cast_x_kernel(const float* __restrict__ in,
                                                     unsigned short* __restrict__ out,
                                                     int n4) {
  int i = blockIdx.x * 256 + threadIdx.x;
  const int stride = gridDim.x * 256;
  for (; i < n4; i += stride) {
    float4 v = ((const float4*)in)[i];
    ushort4 o;
    o.x = f2b(v.x); o.y = f2b(v.y); o.z = f2b(v.z); o.w = f2b(v.w);
    ((ushort4*)out)[i] = o;
  }
}

// ---------------- weight transpose+cast: W[K][N] fp32 -> WT[N][K] bf16 ----------------
__global__ __launch_bounds__(256) void wtrans_kernel(const float* __restrict__ W,
                                                     unsigned short* __restrict__ WT) {
  __shared__ float t[64][65];
  const int k0 = blockIdx.x * 64, n0 = blockIdx.y * 64;
  const int tid = threadIdx.x;
  const int rr = tid >> 4, cc = (tid & 15) * 4;
  for (int p = 0; p < 4; ++p) {
    int row = p * 16 + rr;
    float4 v = *(const float4*)&W[(size_t)(k0 + row) * E_DIM + n0 + cc];
    t[row][cc] = v.x; t[row][cc + 1] = v.y; t[row][cc + 2] = v.z; t[row][cc + 3] = v.w;
  }
  __syncthreads();
  for (int p = 0; p < 4; ++p) {
    int nrow = p * 16 + rr;
    ushort4 o;
    o.x = f2b(t[cc][nrow]); o.y = f2b(t[cc + 1][nrow]);
    o.z = f2b(t[cc + 2][nrow]); o.w = f2b(t[cc + 3][nrow]);
    *(ushort4*)&WT[(size_t)(n0 + nrow) * E_DIM + k0 + cc] = o;
  }
}

// ---------------- GEMM: C[M][N] = A[M][K](bf16) @ BT[N][K](bf16)^T + bias ----------------
// 128x128 tile, BK=64, 4 waves (2x2), global_load_lds staging, 16x16x32 bf16 MFMA.
template <int OUTF32>
__global__ __launch_bounds__(256) void gemm_bt_bias(const unsigned short* __restrict__ A,
                                                    const unsigned short* __restrict__ BT,
                                                    const float* __restrict__ bias,
                                                    void* __restrict__ Cv,
                                                    int M, int N, int K) {
  __shared__ unsigned short Al[128 * 64];
  __shared__ unsigned short Bl[128 * 64];
  const int tid = threadIdx.x;
  const int lane = tid & 63;
  const int wave = tid >> 6;
  const int wr = wave >> 1, wc = wave & 1;
  const int m0 = blockIdx.x * 128, n0 = blockIdx.y * 128;

  f32x4 acc[4][4] = {};

  const int srow = tid >> 3;       // 0..31  (row within 32-row staging pass)
  const int scol = (tid & 7) * 8;  // element offset (8 bf16 = 16B)
  const int koff_base = (lane >> 4) * 8;
  const int lrow = lane & 15;

  for (int k0 = 0; k0 < K; k0 += 64) {
    for (int p = 0; p < 4; ++p) {
      int row = p * 32 + srow;
      // LDS dest: linear, wave-uniform base + lane*16 (required by global_load_lds)
      gld16((const void*)(A + (size_t)(m0 + row) * K + k0 + scol),
            (void*)(Al + p * 2048 + wave * 512));
      gld16((const void*)(BT + (size_t)(n0 + row) * K + k0 + scol),
            (void*)(Bl + p * 2048 + wave * 512));
    }
    __syncthreads();
    for (int ks = 0; ks < 2; ++ks) {
      const int koff = ks * 32 + koff_base;
      s16x8 af[4], bf_[4];
      for (int i = 0; i < 4; ++i)
        af[i] = *(const s16x8*)&Al[(wr * 64 + i * 16 + lrow) * 64 + koff];
      for (int j = 0; j < 4; ++j)
        bf_[j] = *(const s16x8*)&Bl[(wc * 64 + j * 16 + lrow) * 64 + koff];
      for (int i = 0; i < 4; ++i)
        for (int j = 0; j < 4; ++j)
          acc[i][j] = __builtin_amdgcn_mfma_f32_16x16x32_bf16(af[i], bf_[j], acc[i][j], 0, 0, 0);
    }
    __syncthreads();
  }

  // epilogue: C/D layout col=lane&15, row=(lane>>4)*4+reg  [HW-verified m89/m91]
  for (int j = 0; j < 4; ++j) {
    int col = n0 + wc * 64 + j * 16 + lrow;
    float bv = bias[col];
    for (int i = 0; i < 4; ++i) {
      int r0 = m0 + wr * 64 + i * 16 + ((lane >> 4) << 2);
      for (int r = 0; r < 4; ++r) {
        float val = acc[i][j][r] + bv;
        if (OUTF32)
          ((float*)Cv)[(size_t)(r0 + r) * N + col] = val;
        else
          ((unsigned short*)Cv)[(size_t)(r0 + r) * N + col] = f2b(val);
      }
    }
  }
}

// ---------------- causal flash attention ----------------
// Q/K/V/O all bf16 [B,S,E] with head h occupying cols h*64..h*64+63.
// Block: 4 waves, 64 Q rows (wave w -> rows q0+w*16..+15). KV tile = 64 keys.
__global__ __launch_bounds__(256) void attn_kernel(const unsigned short* __restrict__ Qb,
                                                   const unsigned short* __restrict__ Kb,
                                                   const unsigned short* __restrict__ Vb,
                                                   unsigned short* __restrict__ Ob) {
  __shared__ unsigned short VT[64][64];      // V^T tile: VT[d][k]
  __shared__ unsigned short Pl[4][16][64];   // per-wave P tile (row-major [q16][k64])
  const int tid = threadIdx.x, lane = tid & 63, wave = tid >> 6;
  const int q0 = blockIdx.x * 64;
  const int bh = blockIdx.y;
  const size_t base = (size_t)(bh >> 4) * SEQ * E_DIM + (size_t)(bh & 15) * HEAD_D;

  const int lrow = lane & 15, lgrp = lane >> 4;

  // Q fragments (held for the whole block)
  s16x8 qf[2];
  {
    const unsigned short* qp = Qb + base + (size_t)(q0 + wave * 16 + lrow) * E_DIM + lgrp * 8;
    qf[0] = *(const s16x8*)(qp);
    qf[1] = *(const s16x8*)(qp + 32);
  }

  float m_r[4] = {-1e30f, -1e30f, -1e30f, -1e30f};
  float l_r[4] = {0.f, 0.f, 0.f, 0.f};
  f32x4 oacc[4] = {};
  const float scale = 0.125f;  // 1/sqrt(64)

  const int kr = tid >> 4;          // V staging: row within pass
  const int dc = (tid & 15) * 4;    // V staging: d col (4 elems)

  for (int k0 = 0; k0 <= q0; k0 += 64) {
    __syncthreads();  // protect VT from previous iteration's readers
    // stage V tile transposed into LDS
    for (int p = 0; p < 4; ++p) {
      int krow = p * 16 + kr;
      ushort4 v = *(const ushort4*)&Vb[base + (size_t)(k0 + krow) * E_DIM + dc];
      VT[dc][krow] = v.x; VT[dc + 1][krow] = v.y;
      VT[dc + 2][krow] = v.z; VT[dc + 3][krow] = v.w;
    }
    // QK^T: S[16q x 64k] per wave; K B-frags straight from global (L2-resident)
    f32x4 sacc[4] = {};
    for (int jb = 0; jb < 4; ++jb) {
      const unsigned short* kp = Kb + base + (size_t)(k0 + jb * 16 + lrow) * E_DIM + lgrp * 8;
      s16x8 kf0 = *(const s16x8*)(kp);
      s16x8 kf1 = *(const s16x8*)(kp + 32);
      sacc[jb] = __builtin_amdgcn_mfma_f32_16x16x32_bf16(qf[0], kf0, sacc[jb], 0, 0, 0);
      sacc[jb] = __builtin_amdgcn_mfma_f32_16x16x32_bf16(qf[1], kf1, sacc[jb], 0, 0, 0);
    }
    __syncthreads();  // VT fully staged before PV reads

    // scale + causal mask (only diagonal tile needs it)
    float sv[4][4];
    const bool diag = (k0 == q0);
    for (int jb = 0; jb < 4; ++jb)
      for (int r = 0; r < 4; ++r) {
        float v = sacc[jb][r] * scale;
        if (diag) {
          int qq = wave * 16 + lgrp * 4 + r;
          int kk = jb * 16 + lrow;
          if (kk > qq) v = -1e30f;
        }
        sv[jb][r] = v;
      }

    // online softmax: row r lives on the 16 lanes sharing lgrp; reduce over lane bits 0-3
    float mx[4];
    for (int r = 0; r < 4; ++r)
      mx[r] = fmaxf(fmaxf(sv[0][r], sv[1][r]), fmaxf(sv[2][r], sv[3][r]));
    for (int off = 1; off < 16; off <<= 1)
      for (int r = 0; r < 4; ++r)
        mx[r] = fmaxf(mx[r], __shfl_xor(mx[r], off, 64));

    float corr[4], rs[4];
    for (int r = 0; r < 4; ++r) {
      float mn = fmaxf(m_r[r], mx[r]);
      corr[r] = __expf(m_r[r] - mn);
      m_r[r] = mn;
      rs[r] = 0.f;
    }
    for (int jb = 0; jb < 4; ++jb)
      for (int r = 0; r < 4; ++r) {
        float p = __expf(sv[jb][r] - m_r[r]);
        sv[jb][r] = p;
        rs[r] += p;
      }
    for (int off = 1; off < 16; off <<= 1)
      for (int r = 0; r < 4; ++r)
        rs[r] += __shfl_xor(rs[r], off, 64);
    for (int r = 0; r < 4; ++r)
      l_r[r] = l_r[r] * corr[r] + rs[r];
    for (int d = 0; d < 4; ++d) {
      f32x4 o = oacc[d];
      o[0] *= corr[0]; o[1] *= corr[1]; o[2] *= corr[2]; o[3] *= corr[3];
      oacc[d] = o;
    }

    // P -> per-wave LDS (bf16), then PV MFMAs (same-wave LDS RAW is in-order)
    for (int jb = 0; jb < 4; ++jb)
      for (int r = 0; r < 4; ++r)
        Pl[wave][lgrp * 4 + r][jb * 16 + lrow] = f2b(sv[jb][r]);
    for (int ks = 0; ks < 2; ++ks) {
      s16x8 pf = *(const s16x8*)&Pl[wave][lrow][ks * 32 + lgrp * 8];
      for (int d = 0; d < 4; ++d) {
        s16x8 vf = *(const s16x8*)&VT[d * 16 + lrow][ks * 32 + lgrp * 8];
        oacc[d] = __builtin_amdgcn_mfma_f32_16x16x32_bf16(pf, vf, oacc[d], 0, 0, 0);
      }
    }
  }

  // epilogue: O = oacc / l, back to [B,S,E] bf16
  for (int d = 0; d < 4; ++d) {
    int col = d * 16 + lrow;
    for (int r = 0; r < 4; ++r) {
      int row = q0 + wave * 16 + lgrp * 4 + r;
      float val = oacc[d][r] / l_r[r];
      Ob[base + (size_t)row * E_DIM + col] = f2b(val);
    }
  }
}

extern "C" void kernel_launch(void* const* d_in, const int* in_sizes, int n_in,
                              void* d_out, int out_size, void* d_ws, size_t ws_size,
                              hipStream_t stream) {
  const float* x    = (const float*)d_in[0];
  const float* wq_w = (const float*)d_in[1];
  const float* wq_b = (const float*)d_in[2];
  const float* wk_w = (const float*)d_in[3];
  const float* wk_b = (const float*)d_in[4];
  const float* wv_w = (const float*)d_in[5];
  const float* wv_b = (const float*)d_in[6];
  const float* wo_w = (const float*)d_in[7];
  const float* wo_b = (const float*)d_in[8];
  float* out = (float*)d_out;

  const size_t XE = (size_t)M_ROWS * E_DIM;  // 8192*1024
  char* ws = (char*)d_ws;
  unsigned short* xb  = (unsigned short*)ws;            ws += XE * 2;
  unsigned short* wqT = (unsigned short*)ws;            ws += (size_t)E_DIM * E_DIM * 2;
  unsigned short* wkT = (unsigned short*)ws;            ws += (size_t)E_DIM * E_DIM * 2;
  unsigned short* wvT = (unsigned short*)ws;            ws += (size_t)E_DIM * E_DIM * 2;
  unsigned short* woT = (unsigned short*)ws;            ws += (size_t)E_DIM * E_DIM * 2;
  unsigned short* Qb  = (unsigned short*)ws;            ws += XE * 2;
  unsigned short* Kb  = (unsigned short*)ws;            ws += XE * 2;
  unsigned short* Vb  = (unsigned short*)ws;            ws += XE * 2;
  unsigned short* Ao  = (unsigned short*)ws;            ws += XE * 2;

  cast_x_kernel<<<2048, 256, 0, stream>>>(x, xb, (int)(XE / 4));
  dim3 tg(E_DIM / 64, E_DIM / 64);
  wtrans_kernel<<<tg, 256, 0, stream>>>(wq_w, wqT);
  wtrans_kernel<<<tg, 256, 0, stream>>>(wk_w, wkT);
  wtrans_kernel<<<tg, 256, 0, stream>>>(wv_w, wvT);
  wtrans_kernel<<<tg, 256, 0, stream>>>(wo_w, woT);

  dim3 gg(M_ROWS / 128, E_DIM / 128);
  gemm_bt_bias<0><<<gg, 256, 0, stream>>>(xb, wqT, wq_b, Qb, M_ROWS, E_DIM, E_DIM);
  gemm_bt_bias<0><<<gg, 256, 0, stream>>>(xb, wkT, wk_b, Kb, M_ROWS, E_DIM, E_DIM);
  gemm_bt_bias<0><<<gg, 256, 0, stream>>>(xb, wvT, wv_b, Vb, M_ROWS, E_DIM, E_DIM);

  attn_kernel<<<dim3(SEQ / 64, BATCH * N_HEADS), 256, 0, stream>>>(Qb, Kb, Vb, Ao);

  gemm_bt_bias<1><<<gg, 256, 0, stream>>>(Ao, woT, wo_b, out, M_ROWS, E_DIM, E_DIM);
}

// Round 2
// 400.283 us; speedup vs baseline: 1.4226x; 1.4226x over previous
//
#include <hip/hip_runtime.h>

// Problem constants (CausalMultiHeadSelfAttention): B=4, S=2048, E=1024, H=16, D=64
#define E_DIM 1024
#define N_HEADS 16
#define HEAD_D 64
#define BATCH 4
#define SEQ 2048
#define M_ROWS (BATCH * SEQ)  // 8192

typedef __attribute__((ext_vector_type(4))) float f32x4;
typedef __attribute__((ext_vector_type(8))) short s16x8;  // 8 bf16 in 4 VGPRs

__device__ __forceinline__ unsigned short f2b(float f) {
  union { float f; unsigned u; } v; v.f = f;
  unsigned r = v.u + 0x7fffu + ((v.u >> 16) & 1u);  // RNE
  return (unsigned short)(r >> 16);
}

__device__ __forceinline__ void gld16(const void* g, void* l) {
  __builtin_amdgcn_global_load_lds(
      (__attribute__((address_space(1))) void*)(g),
      (__attribute__((address_space(3))) void*)(l), 16, 0, 0);
}

// ---------------- cast x (fp32 -> bf16), vectorized ----------------
__global__ __launch_bounds__(256) void cast_x_kernel(const float* __restrict__ in,
                                                     unsigned short* __restrict__ out,
                                                     int n4) {
  int i = blockIdx.x * 256 + threadIdx.x;
  const int stride = gridDim.x * 256;
  for (; i < n4; i += stride) {
    float4 v = ((const float4*)in)[i];
    ushort4 o;
    o.x = f2b(v.x); o.y = f2b(v.y); o.z = f2b(v.z); o.w = f2b(v.w);
    ((ushort4*)out)[i] = o;
  }
}

// ---------------- weight transpose+cast: W[K][N] fp32 -> WT[N][K] bf16 ----------------
__global__ __launch_bounds__(256) void wtrans_kernel(const float* __restrict__ W,
                                                     unsigned short* __restrict__ WT) {
  __shared__ float t[64][65];
  const int k0 = blockIdx.x * 64, n0 = blockIdx.y * 64;
  const int tid = threadIdx.x;
  const int rr = tid >> 4, cc = (tid & 15) * 4;
  for (int p = 0; p < 4; ++p) {
    int row = p * 16 + rr;
    float4 v = *(const float4*)&W[(size_t)(k0 + row) * E_DIM + n0 + cc];
    t[row][cc] = v.x; t[row][cc + 1] = v.y; t[row][cc + 2] = v.z; t[row][cc + 3] = v.w;
  }
  __syncthreads();
  for (int p = 0; p < 4; ++p) {
    int nrow = p * 16 + rr;
    ushort4 o;
    o.x = f2b(t[cc][nrow]); o.y = f2b(t[cc + 1][nrow]);
    o.z = f2b(t[cc + 2][nrow]); o.w = f2b(t[cc + 3][nrow]);
    *(ushort4*)&WT[(size_t)(n0 + nrow) * E_DIM + k0 + cc] = o;
  }
}

// ---------------- GEMM: C[M][N] = A[M][K](bf16) @ BT[N][K](bf16)^T + bias ----------------
// 128x128 tile, BK=64, 4 waves (2x2), global_load_lds staging, 16x16x32 bf16 MFMA.
// OUTMODE: 0 = bf16 row-major [M][N]; 1 = f32 row-major; 2 = bf16 per-head transposed
//          Vt[(b*16+h)][d][s]  (b = m>>11, s = m&2047, h = n>>6, d = n&63)
template <int OUTMODE>
__global__ __launch_bounds__(256) void gemm_bt_bias(const unsigned short* __restrict__ A,
                                                    const unsigned short* __restrict__ BT,
                                                    const float* __restrict__ bias,
                                                    void* __restrict__ Cv,
                                                    int M, int N, int K) {
  __shared__ unsigned short Al[128 * 64];
  __shared__ unsigned short Bl[128 * 64];
  const int tid = threadIdx.x;
  const int lane = tid & 63;
  const int wave = tid >> 6;
  const int wr = wave >> 1, wc = wave & 1;
  const int m0 = blockIdx.x * 128, n0 = blockIdx.y * 128;

  f32x4 acc[4][4] = {};

  const int srow = tid >> 3;       // 0..31  (row within 32-row staging pass)
  const int scol = (tid & 7) * 8;  // element offset (8 bf16 = 16B)
  const int koff_base = (lane >> 4) * 8;
  const int lrow = lane & 15;

  for (int k0 = 0; k0 < K; k0 += 64) {
    for (int p = 0; p < 4; ++p) {
      int row = p * 32 + srow;
      gld16((const void*)(A + (size_t)(m0 + row) * K + k0 + scol),
            (void*)(Al + p * 2048 + wave * 512));
      gld16((const void*)(BT + (size_t)(n0 + row) * K + k0 + scol),
            (void*)(Bl + p * 2048 + wave * 512));
    }
    __syncthreads();
    for (int ks = 0; ks < 2; ++ks) {
      const int koff = ks * 32 + koff_base;
      s16x8 af[4], bf_[4];
      for (int i = 0; i < 4; ++i)
        af[i] = *(const s16x8*)&Al[(wr * 64 + i * 16 + lrow) * 64 + koff];
      for (int j = 0; j < 4; ++j)
        bf_[j] = *(const s16x8*)&Bl[(wc * 64 + j * 16 + lrow) * 64 + koff];
      for (int i = 0; i < 4; ++i)
        for (int j = 0; j < 4; ++j)
          acc[i][j] = __builtin_amdgcn_mfma_f32_16x16x32_bf16(af[i], bf_[j], acc[i][j], 0, 0, 0);
    }
    __syncthreads();
  }

  // epilogue: C/D layout col=lane&15, row=(lane>>4)*4+reg  [HW-verified m89/m91]
  for (int j = 0; j < 4; ++j) {
    int col = n0 + wc * 64 + j * 16 + lrow;
    float bv = bias[col];
    for (int i = 0; i < 4; ++i) {
      int r0 = m0 + wr * 64 + i * 16 + ((lane >> 4) << 2);
      for (int r = 0; r < 4; ++r) {
        float val = acc[i][j][r] + bv;
        int m = r0 + r;
        if (OUTMODE == 1) {
          ((float*)Cv)[(size_t)m * N + col] = val;
        } else if (OUTMODE == 0) {
          ((unsigned short*)Cv)[(size_t)m * N + col] = f2b(val);
        } else {  // transposed per-head for V
          int b = m >> 11, s = m & 2047;
          int h = col >> 6, d = col & 63;
          ((unsigned short*)Cv)[((size_t)(b * 16 + h) * HEAD_D + d) * SEQ + s] = f2b(val);
        }
      }
    }
  }
}

// ---------------- causal flash attention v2 (barrier-free) ----------------
// Q,K bf16 [B,S,E] (head h at cols h*64..); V pre-transposed: Vt[bh][d][s].
// Block = 256 threads = 4 independent waves; wave w owns 32 q-rows
// [qb*128 + w*32, +32). KV tile = 64 keys. No __syncthreads anywhere.
// Only LDS: per-wave P round-trip (32x64 bf16), XOR-swizzled.
__global__ __launch_bounds__(256) void attn2_kernel(const unsigned short* __restrict__ Qb,
                                                    const unsigned short* __restrict__ Kb,
                                                    const unsigned short* __restrict__ Vt,
                                                    unsigned short* __restrict__ Ob) {
  __shared__ unsigned short Pl[4][32 * 64];  // 4 KB per wave, swizzled
  const int tid = threadIdx.x, lane = tid & 63, wave = tid >> 6;
  const int qb = gridDim.x - 1 - blockIdx.x;  // longest blocks first
  const int bh = blockIdx.y;
  const size_t base = (size_t)(bh >> 4) * SEQ * E_DIM + (size_t)(bh & 15) * HEAD_D;
  const size_t baset = (size_t)bh * HEAD_D * SEQ;
  const int lrow = lane & 15, lgrp = lane >> 4;
  const int qs = qb * 128 + wave * 32;  // this wave's first q row
  char* Pw = (char*)&Pl[wave][0];

  // Q fragments: rows qs + qi*16 + lrow, d-runs lgrp*8 and 32+lgrp*8
  s16x8 qf[2][2];
  for (int qi = 0; qi < 2; ++qi) {
    const unsigned short* qp = Qb + base + (size_t)(qs + qi * 16 + lrow) * E_DIM + lgrp * 8;
    qf[qi][0] = *(const s16x8*)(qp);
    qf[qi][1] = *(const s16x8*)(qp + 32);
  }

  float m_r[2][4], l_r[2][4];
  f32x4 oacc[2][4] = {};
  for (int qi = 0; qi < 2; ++qi)
    for (int r = 0; r < 4; ++r) { m_r[qi][r] = -1e30f; l_r[qi][r] = 0.f; }

  // softmax in exp2 domain: 2^((s-m)*scale2) == e^((s-m)/8)
  const float scale2 = 0.125f * 1.44269504089f;
  const int nt = ((qs + 31) >> 6) + 1;  // causal tile count for this wave

  for (int t = 0; t < nt; ++t) {
    const int k0 = t * 64;
    // K B-frags: lane -> key jb*16+lrow, d-run ks*32+lgrp*8  (L2-resident)
    s16x8 kf[4][2];
    for (int jb = 0; jb < 4; ++jb) {
      const unsigned short* kp = Kb + base + (size_t)(k0 + jb * 16 + lrow) * E_DIM + lgrp * 8;
      kf[jb][0] = *(const s16x8*)(kp);
      kf[jb][1] = *(const s16x8*)(kp + 32);
    }
    // V B-frags from transposed global: lane -> d row db*16+lrow, k-run ks*32+lgrp*8
    s16x8 vf[4][2];
    for (int db = 0; db < 4; ++db) {
      const unsigned short* vp = Vt + baset + (size_t)(db * 16 + lrow) * SEQ + k0 + lgrp * 8;
      vf[db][0] = *(const s16x8*)(vp);
      vf[db][1] = *(const s16x8*)(vp + 32);
    }

    // QK^T: S[32q][64k] per wave
    f32x4 sacc[2][4] = {};
    for (int qi = 0; qi < 2; ++qi)
      for (int jb = 0; jb < 4; ++jb) {
        sacc[qi][jb] = __builtin_amdgcn_mfma_f32_16x16x32_bf16(qf[qi][0], kf[jb][0], sacc[qi][jb], 0, 0, 0);
        sacc[qi][jb] = __builtin_amdgcn_mfma_f32_16x16x32_bf16(qf[qi][1], kf[jb][1], sacc[qi][jb], 0, 0, 0);
      }

    // scale (exp2 domain) + causal mask (only the final tile of this wave)
    float sv[2][4][4];
    const bool diag = (t == nt - 1);
    for (int qi = 0; qi < 2; ++qi)
      for (int jb = 0; jb < 4; ++jb)
        for (int r = 0; r < 4; ++r) {
          float v = sacc[qi][jb][r] * scale2;
          if (diag) {
            int qq = qs + qi * 16 + lgrp * 4 + r;
            int kk = k0 + jb * 16 + lrow;
            if (kk > qq) v = -1e30f;
          }
          sv[qi][jb][r] = v;
        }

    // online softmax: row q lives on the 16 lanes sharing lgrp (vary lane bits 0-3)
    for (int qi = 0; qi < 2; ++qi) {
      float mx[4];
      for (int r = 0; r < 4; ++r)
        mx[r] = fmaxf(fmaxf(sv[qi][0][r], sv[qi][1][r]), fmaxf(sv[qi][2][r], sv[qi][3][r]));
      for (int off = 1; off < 16; off <<= 1)
        for (int r = 0; r < 4; ++r)
          mx[r] = fmaxf(mx[r], __shfl_xor(mx[r], off, 64));
      float corr[4], rs[4];
      for (int r = 0; r < 4; ++r) {
        float mn = fmaxf(m_r[qi][r], mx[r]);
        corr[r] = __builtin_amdgcn_exp2f(m_r[qi][r] - mn);
        m_r[qi][r] = mn;
        rs[r] = 0.f;
      }
      for (int jb = 0; jb < 4; ++jb)
        for (int r = 0; r < 4; ++r) {
          float p = __builtin_amdgcn_exp2f(sv[qi][jb][r] - m_r[qi][r]);
          sv[qi][jb][r] = p;
          rs[r] += p;
        }
      for (int off = 1; off < 16; off <<= 1)
        for (int r = 0; r < 4; ++r)
          rs[r] += __shfl_xor(rs[r], off, 64);
      for (int r = 0; r < 4; ++r)
        l_r[qi][r] = l_r[qi][r] * corr[r] + rs[r];
      for (int db = 0; db < 4; ++db) {
        f32x4 o = oacc[qi][db];
        o[0] *= corr[0]; o[1] *= corr[1]; o[2] *= corr[2]; o[3] *= corr[3];
        oacc[qi][db] = o;
      }
    }

    // P -> per-wave LDS (bf16), XOR-swizzled: byte ^= ((row>>2)&3)<<5.
    // Write banks: ((jb^lgrp)&3)*8 + lrow/2 -> full 32-bank spread (2-way, free).
    for (int qi = 0; qi < 2; ++qi)
      for (int jb = 0; jb < 4; ++jb)
        for (int r = 0; r < 4; ++r) {
          int row = qi * 16 + lgrp * 4 + r;
          int byte = row * 128 + (jb * 16 + lrow) * 2;
          byte ^= ((row >> 2) & 3) << 5;
          *(unsigned short*)(Pw + byte) = f2b(sv[qi][jb][r]);
        }
    // read back as A-frags (same swizzle; 16B blocks relocate contiguously), then PV
    for (int qi = 0; qi < 2; ++qi)
      for (int ks = 0; ks < 2; ++ks) {
        int row = qi * 16 + lrow;
        int byte = row * 128 + (ks * 32 + lgrp * 8) * 2;
        byte ^= ((row >> 2) & 3) << 5;
        s16x8 pf = *(const s16x8*)(Pw + byte);
        for (int db = 0; db < 4; ++db)
          oacc[qi][db] = __builtin_amdgcn_mfma_f32_16x16x32_bf16(pf, vf[db][ks], oacc[qi][db], 0, 0, 0);
      }
  }

  // epilogue: O = oacc / l -> bf16 [B,S,E]
  for (int qi = 0; qi < 2; ++qi) {
    float rl[4];
    for (int r = 0; r < 4; ++r) rl[r] = 1.0f / l_r[qi][r];
    for (int db = 0; db < 4; ++db) {
      int col = db * 16 + lrow;
      for (int r = 0; r < 4; ++r) {
        int row = qs + qi * 16 + lgrp * 4 + r;
        Ob[base + (size_t)row * E_DIM + col] = f2b(oacc[qi][db][r] * rl[r]);
      }
    }
  }
}

extern "C" void kernel_launch(void* const* d_in, const int* in_sizes, int n_in,
                              void* d_out, int out_size, void* d_ws, size_t ws_size,
                              hipStream_t stream) {
  const float* x    = (const float*)d_in[0];
  const float* wq_w = (const float*)d_in[1];
  const float* wq_b = (const float*)d_in[2];
  const float* wk_w = (const float*)d_in[3];
  const float* wk_b = (const float*)d_in[4];
  const float* wv_w = (const float*)d_in[5];
  const float* wv_b = (const float*)d_in[6];
  const float* wo_w = (const float*)d_in[7];
  const float* wo_b = (const float*)d_in[8];
  float* out = (float*)d_out;

  const size_t XE = (size_t)M_ROWS * E_DIM;  // 8192*1024
  char* ws = (char*)d_ws;
  unsigned short* xb  = (unsigned short*)ws;            ws += XE * 2;
  unsigned short* wqT = (unsigned short*)ws;            ws += (size_t)E_DIM * E_DIM * 2;
  unsigned short* wkT = (unsigned short*)ws;            ws += (size_t)E_DIM * E_DIM * 2;
  unsigned short* wvT = (unsigned short*)ws;            ws += (size_t)E_DIM * E_DIM * 2;
  unsigned short* woT = (unsigned short*)ws;            ws += (size_t)E_DIM * E_DIM * 2;
  unsigned short* Qb  = (unsigned short*)ws;            ws += XE * 2;
  unsigned short* Kb  = (unsigned short*)ws;            ws += XE * 2;
  unsigned short* Vt  = (unsigned short*)ws;            ws += XE * 2;  // [bh][d][s]
  unsigned short* Ao  = (unsigned short*)ws;            ws += XE * 2;

  cast_x_kernel<<<2048, 256, 0, stream>>>(x, xb, (int)(XE / 4));
  dim3 tg(E_DIM / 64, E_DIM / 64);
  wtrans_kernel<<<tg, 256, 0, stream>>>(wq_w, wqT);
  wtrans_kernel<<<tg, 256, 0, stream>>>(wk_w, wkT);
  wtrans_kernel<<<tg, 256, 0, stream>>>(wv_w, wvT);
  wtrans_kernel<<<tg, 256, 0, stream>>>(wo_w, woT);

  dim3 gg(M_ROWS / 128, E_DIM / 128);
  gemm_bt_bias<0><<<gg, 256, 0, stream>>>(xb, wqT, wq_b, Qb, M_ROWS, E_DIM, E_DIM);
  gemm_bt_bias<0><<<gg, 256, 0, stream>>>(xb, wkT, wk_b, Kb, M_ROWS, E_DIM, E_DIM);
  gemm_bt_bias<2><<<gg, 256, 0, stream>>>(xb, wvT, wv_b, Vt, M_ROWS, E_DIM, E_DIM);

  attn2_kernel<<<dim3(SEQ / 128, BATCH * N_HEADS), 256, 0, stream>>>(Qb, Kb, Vt, Ao);

  gemm_bt_bias<1><<<gg, 256, 0, stream>>>(Ao, woT, wo_b, out, M_ROWS, E_DIM, E_DIM);
}

// Round 3
// 388.575 us; speedup vs baseline: 1.4655x; 1.0301x over previous
//
#include <hip/hip_runtime.h>
#include <hip/hip_bf16.h>

// Problem constants (CausalMultiHeadSelfAttention): B=4, S=2048, E=1024, H=16, D=64
#define E_DIM 1024
#define N_HEADS 16
#define HEAD_D 64
#define BATCH 4
#define SEQ 2048
#define M_ROWS (BATCH * SEQ)  // 8192

typedef __attribute__((ext_vector_type(4))) float f32x4;
typedef __attribute__((ext_vector_type(8))) short s16x8;  // 8 bf16 in 4 VGPRs

__device__ __forceinline__ unsigned short f2b(float f) {
  union { float f; unsigned u; } v; v.f = f;
  unsigned r = v.u + 0x7fffu + ((v.u >> 16) & 1u);  // RNE
  return (unsigned short)(r >> 16);
}

__device__ __forceinline__ unsigned packbf2(float lo, float hi) {
  union { __hip_bfloat162 h; unsigned u; } p;
  p.h = __float22bfloat162_rn(float2{lo, hi});  // compiler emits v_cvt_pk_bf16_f32
  return p.u;
}

__device__ __forceinline__ void gld16(const void* g, void* l) {
  __builtin_amdgcn_global_load_lds(
      (__attribute__((address_space(1))) void*)(g),
      (__attribute__((address_space(3))) void*)(l), 16, 0, 0);
}

// ---------------- cast x (fp32 -> bf16), vectorized ----------------
__global__ __launch_bounds__(256) void cast_x_kernel(const float* __restrict__ in,
                                                     unsigned short* __restrict__ out,
                                                     int n4) {
  int i = blockIdx.x * 256 + threadIdx.x;
  const int stride = gridDim.x * 256;
  for (; i < n4; i += stride) {
    float4 v = ((const float4*)in)[i];
    ushort4 o;
    o.x = f2b(v.x); o.y = f2b(v.y); o.z = f2b(v.z); o.w = f2b(v.w);
    ((ushort4*)out)[i] = o;
  }
}

// ---------------- weight transpose+cast: W[K][N] fp32 -> WT[N][K] bf16 ----------------
__global__ __launch_bounds__(256) void wtrans_kernel(const float* __restrict__ W,
                                                     unsigned short* __restrict__ WT) {
  __shared__ float t[64][65];
  const int k0 = blockIdx.x * 64, n0 = blockIdx.y * 64;
  const int tid = threadIdx.x;
  const int rr = tid >> 4, cc = (tid & 15) * 4;
  for (int p = 0; p < 4; ++p) {
    int row = p * 16 + rr;
    float4 v = *(const float4*)&W[(size_t)(k0 + row) * E_DIM + n0 + cc];
    t[row][cc] = v.x; t[row][cc + 1] = v.y; t[row][cc + 2] = v.z; t[row][cc + 3] = v.w;
  }
  __syncthreads();
  for (int p = 0; p < 4; ++p) {
    int nrow = p * 16 + rr;
    ushort4 o;
    o.x = f2b(t[cc][nrow]); o.y = f2b(t[cc + 1][nrow]);
    o.z = f2b(t[cc + 2][nrow]); o.w = f2b(t[cc + 3][nrow]);
    *(ushort4*)&WT[(size_t)(n0 + nrow) * E_DIM + k0 + cc] = o;
  }
}

// ---------------- fused QKV GEMM: [8192,1024] x [1024,3072] ----------------
// BT = WqkvT[3072][1024] bf16. Epilogue routes: proj 0 -> Qb (bf16 [M][E]),
// proj 1 -> Kb (bf16 [M][E]), proj 2 -> Vt transposed [(b*16+h)*64+d][s].
__global__ __launch_bounds__(256) void gemm_qkv(const unsigned short* __restrict__ A,
                                                const unsigned short* __restrict__ BT,
                                                const float* __restrict__ bq,
                                                const float* __restrict__ bk,
                                                const float* __restrict__ bv,
                                                unsigned short* __restrict__ Qb,
                                                unsigned short* __restrict__ Kb,
                                                unsigned short* __restrict__ Vt) {
  __shared__ unsigned short Al[128 * 64];
  __shared__ unsigned short Bl[128 * 64];
  const int K = E_DIM;
  const int tid = threadIdx.x;
  const int lane = tid & 63;
  const int wave = tid >> 6;
  const int wr = wave >> 1, wc = wave & 1;
  const int m0 = blockIdx.x * 128, n0 = blockIdx.y * 128;

  f32x4 acc[4][4] = {};
  const int srow = tid >> 3;
  const int scol = (tid & 7) * 8;
  const int koff_base = (lane >> 4) * 8;
  const int lrow = lane & 15;

  for (int k0 = 0; k0 < K; k0 += 64) {
    for (int p = 0; p < 4; ++p) {
      int row = p * 32 + srow;
      gld16((const void*)(A + (size_t)(m0 + row) * K + k0 + scol),
            (void*)(Al + p * 2048 + wave * 512));
      gld16((const void*)(BT + (size_t)(n0 + row) * K + k0 + scol),
            (void*)(Bl + p * 2048 + wave * 512));
    }
    __syncthreads();
    for (int ks = 0; ks < 2; ++ks) {
      const int koff = ks * 32 + koff_base;
      s16x8 af[4], bf_[4];
      for (int i = 0; i < 4; ++i)
        af[i] = *(const s16x8*)&Al[(wr * 64 + i * 16 + lrow) * 64 + koff];
      for (int j = 0; j < 4; ++j)
        bf_[j] = *(const s16x8*)&Bl[(wc * 64 + j * 16 + lrow) * 64 + koff];
      for (int i = 0; i < 4; ++i)
        for (int j = 0; j < 4; ++j)
          acc[i][j] = __builtin_amdgcn_mfma_f32_16x16x32_bf16(af[i], bf_[j], acc[i][j], 0, 0, 0);
    }
    __syncthreads();
  }

  for (int j = 0; j < 4; ++j) {
    int c = n0 + wc * 64 + j * 16 + lrow;   // global col in [0,3072)
    int proj = c >> 10, cc = c & 1023;
    float bvl = (proj == 0) ? bq[cc] : (proj == 1) ? bk[cc] : bv[cc];
    for (int i = 0; i < 4; ++i) {
      int r0 = m0 + wr * 64 + i * 16 + ((lane >> 4) << 2);
      for (int r = 0; r < 4; ++r) {
        float val = acc[i][j][r] + bvl;
        int m = r0 + r;
        if (proj == 0) {
          Qb[(size_t)m * E_DIM + cc] = f2b(val);
        } else if (proj == 1) {
          Kb[(size_t)m * E_DIM + cc] = f2b(val);
        } else {
          int b = m >> 11, s = m & 2047;
          int h = cc >> 6, d = cc & 63;
          Vt[((size_t)((b * 16 + h) * 64 + d)) * SEQ + s] = f2b(val);
        }
      }
    }
  }
}

// ---------------- plain GEMM (output projection): f32 out ----------------
__global__ __launch_bounds__(256) void gemm_out(const unsigned short* __restrict__ A,
                                                const unsigned short* __restrict__ BT,
                                                const float* __restrict__ bias,
                                                float* __restrict__ C) {
  __shared__ unsigned short Al[128 * 64];
  __shared__ unsigned short Bl[128 * 64];
  const int K = E_DIM, N = E_DIM;
  const int tid = threadIdx.x;
  const int lane = tid & 63;
  const int wave = tid >> 6;
  const int wr = wave >> 1, wc = wave & 1;
  const int m0 = blockIdx.x * 128, n0 = blockIdx.y * 128;

  f32x4 acc[4][4] = {};
  const int srow = tid >> 3;
  const int scol = (tid & 7) * 8;
  const int koff_base = (lane >> 4) * 8;
  const int lrow = lane & 15;

  for (int k0 = 0; k0 < K; k0 += 64) {
    for (int p = 0; p < 4; ++p) {
      int row = p * 32 + srow;
      gld16((const void*)(A + (size_t)(m0 + row) * K + k0 + scol),
            (void*)(Al + p * 2048 + wave * 512));
      gld16((const void*)(BT + (size_t)(n0 + row) * K + k0 + scol),
            (void*)(Bl + p * 2048 + wave * 512));
    }
    __syncthreads();
    for (int ks = 0; ks < 2; ++ks) {
      const int koff = ks * 32 + koff_base;
      s16x8 af[4], bf_[4];
      for (int i = 0; i < 4; ++i)
        af[i] = *(const s16x8*)&Al[(wr * 64 + i * 16 + lrow) * 64 + koff];
      for (int j = 0; j < 4; ++j)
        bf_[j] = *(const s16x8*)&Bl[(wc * 64 + j * 16 + lrow) * 64 + koff];
      for (int i = 0; i < 4; ++i)
        for (int j = 0; j < 4; ++j)
          acc[i][j] = __builtin_amdgcn_mfma_f32_16x16x32_bf16(af[i], bf_[j], acc[i][j], 0, 0, 0);
    }
    __syncthreads();
  }

  for (int j = 0; j < 4; ++j) {
    int col = n0 + wc * 64 + j * 16 + lrow;
    float bvl = bias[col];
    for (int i = 0; i < 4; ++i) {
      int r0 = m0 + wr * 64 + i * 16 + ((lane >> 4) << 2);
      for (int r = 0; r < 4; ++r)
        C[(size_t)(r0 + r) * N + col] = acc[i][j][r] + bvl;
    }
  }
}

// ---------------- causal flash attention v3 ----------------
// Swapped-operand form: S^T = mfma(K, Q) puts P lane-local (q = lane&15).
// O^T = mfma(V^T, P^T) with V^T A-frags straight from Vt[bh][d][s].
// P^T B-frags built in-register via a 2-level shfl_xor butterfly (no LDS at all).
// Row-sum l via mfma(ones, P^T) accumulator rescaled like O.
// Causal balance: block pairs q-chunk i with chunk 31-i -> every wave does
// exactly 33 tile-halves. Zero __shared__; 4 waves/SIMD via launch_bounds.
__global__ __launch_bounds__(256, 4) void attn3_kernel(const unsigned short* __restrict__ Qb,
                                                       const unsigned short* __restrict__ Kb,
                                                       const unsigned short* __restrict__ Vt,
                                                       unsigned short* __restrict__ Ob) {
  const int tid = threadIdx.x, lane = tid & 63, wave = tid >> 6;
  const int ip = blockIdx.x;  // pair index 0..15: chunks ip and 31-ip
  const int bh = blockIdx.y;
  const size_t base = (size_t)(bh >> 4) * SEQ * E_DIM + (size_t)(bh & 15) * HEAD_D;
  const size_t baset = (size_t)bh * HEAD_D * SEQ;
  const int lq = lane & 15, lg = lane >> 4;

  const int row_lo = ip * 64 + wave * 16 + lq;         // qi=0 q-row
  const int row_hi = (31 - ip) * 64 + wave * 16 + lq;  // qi=1 q-row

  // Q B-frags (row = lane&15, d-run = lg*8 / 32+lg*8)
  s16x8 qf0[2], qf1[2];
  {
    const unsigned short* p0 = Qb + base + (size_t)row_lo * E_DIM + lg * 8;
    qf0[0] = *(const s16x8*)p0; qf0[1] = *(const s16x8*)(p0 + 32);
    const unsigned short* p1 = Qb + base + (size_t)row_hi * E_DIM + lg * 8;
    qf1[0] = *(const s16x8*)p1; qf1[1] = *(const s16x8*)(p1 + 32);
  }

  const short onebf = (short)0x3F80;
  const s16x8 ones = {onebf, onebf, onebf, onebf, onebf, onebf, onebf, onebf};

  float m0r = -1e30f, m1r = -1e30f;
  f32x4 o0[4] = {}, o1[4] = {};
  f32x4 l0 = {}, l1 = {};
  const float scale2 = 0.125f * 1.44269504089f;  // exp2 domain
  const int ntm1 = 31 - ip;
  const bool hi5 = (lane & 32) != 0, hi4 = (lane & 16) != 0;

  int k0 = 0;
  for (int t = 0; t <= ntm1; ++t, k0 += 64) {
    // K A-frags (row k = lane&15 within jb block, d-run lg*8)
    s16x8 kf[4][2];
#pragma unroll
    for (int jb = 0; jb < 4; ++jb) {
      const unsigned short* kp = Kb + base + (size_t)(k0 + jb * 16 + lq) * E_DIM + lg * 8;
      kf[jb][0] = *(const s16x8*)kp;
      kf[jb][1] = *(const s16x8*)(kp + 32);
    }
    const bool do0 = (t <= ip);
    // swapped QK^T: sacc[kb] holds S^T rows k = k0+kb*16+lg*4+r, col q = lq
    f32x4 s1v[4] = {}, s0v[4] = {};
#pragma unroll
    for (int kb = 0; kb < 4; ++kb) {
      s1v[kb] = __builtin_amdgcn_mfma_f32_16x16x32_bf16(kf[kb][0], qf1[0], s1v[kb], 0, 0, 0);
      s1v[kb] = __builtin_amdgcn_mfma_f32_16x16x32_bf16(kf[kb][1], qf1[1], s1v[kb], 0, 0, 0);
    }
    if (do0) {
#pragma unroll
      for (int kb = 0; kb < 4; ++kb) {
        s0v[kb] = __builtin_amdgcn_mfma_f32_16x16x32_bf16(kf[kb][0], qf0[0], s0v[kb], 0, 0, 0);
        s0v[kb] = __builtin_amdgcn_mfma_f32_16x16x32_bf16(kf[kb][1], qf0[1], s0v[kb], 0, 0, 0);
      }
    }
    // V^T A-frags (row d = db*16+lane&15, k-run k0+ks*32+lg*8)
    s16x8 vf[4][2];
#pragma unroll
    for (int db = 0; db < 4; ++db) {
      const unsigned short* vp = Vt + baset + (size_t)(db * 16 + lq) * SEQ + k0 + lg * 8;
      vf[db][0] = *(const s16x8*)vp;
      vf[db][1] = *(const s16x8*)(vp + 32);
    }

    auto process = [&](f32x4 (&sv)[4], int qrow, bool diag, float& mreg,
                       f32x4 (&oacc)[4], f32x4& lacc) {
      // scale (+ causal mask on the diagonal tile)
      float p[4][4];
#pragma unroll
      for (int kb = 0; kb < 4; ++kb)
#pragma unroll
        for (int r = 0; r < 4; ++r) {
          float v = sv[kb][r] * scale2;
          if (diag) {
            int kk = k0 + kb * 16 + lg * 4 + r;
            if (kk > qrow) v = -1e30f;
          }
          p[kb][r] = v;
        }
      // row max: 15 in-register + 2 cross-group shuffles
      float mx = p[0][0];
#pragma unroll
      for (int kb = 0; kb < 4; ++kb)
#pragma unroll
        for (int r = 0; r < 4; ++r) mx = fmaxf(mx, p[kb][r]);
      mx = fmaxf(mx, __shfl_xor(mx, 16, 64));
      mx = fmaxf(mx, __shfl_xor(mx, 32, 64));
      float mn = fmaxf(mreg, mx);
      float corr = __builtin_amdgcn_exp2f(mreg - mn);
      mreg = mn;
      // exp + pack pairs (bf16x2 words) c[kb][rp]
      unsigned c[4][2];
#pragma unroll
      for (int kb = 0; kb < 4; ++kb)
#pragma unroll
        for (int rp = 0; rp < 2; ++rp) {
          float plo = __builtin_amdgcn_exp2f(p[kb][2 * rp] - mn);
          float phi = __builtin_amdgcn_exp2f(p[kb][2 * rp + 1] - mn);
          c[kb][rp] = packbf2(plo, phi);
        }
      // butterfly B1: swap lane-bit5 <-> reg-bit kb0
#pragma unroll
      for (int k1 = 0; k1 < 2; ++k1)
#pragma unroll
        for (int rp = 0; rp < 2; ++rp) {
          unsigned a = c[2 * k1][rp], b = c[2 * k1 + 1][rp];
          unsigned x = hi5 ? a : b;
          x = __shfl_xor(x, 32, 64);
          c[2 * k1][rp] = hi5 ? x : a;
          c[2 * k1 + 1][rp] = hi5 ? b : x;
        }
      // butterfly B2: swap lane-bit4 <-> reg-bit (now s1)
#pragma unroll
      for (int k1 = 0; k1 < 2; ++k1)
#pragma unroll
        for (int rp = 0; rp < 2; ++rp) {
          unsigned a = c[2 * k1][rp], b = c[2 * k1 + 1][rp];
          unsigned x = hi4 ? a : b;
          x = __shfl_xor(x, 16, 64);
          c[2 * k1][rp] = hi4 ? x : a;
          c[2 * k1 + 1][rp] = hi4 ? b : x;
        }
      // rescale accumulators
#pragma unroll
      for (int db = 0; db < 4; ++db) oacc[db] = oacc[db] * corr;
      lacc = lacc * corr;
      // PV + row-sum: pf[ks] words = (c[2ks][0], c[2ks][1], c[2ks+1][0], c[2ks+1][1])
#pragma unroll
      for (int ks = 0; ks < 2; ++ks) {
        union { unsigned w[4]; s16x8 v; } pu;
        pu.w[0] = c[2 * ks][0]; pu.w[1] = c[2 * ks][1];
        pu.w[2] = c[2 * ks + 1][0]; pu.w[3] = c[2 * ks + 1][1];
        lacc = __builtin_amdgcn_mfma_f32_16x16x32_bf16(ones, pu.v, lacc, 0, 0, 0);
#pragma unroll
        for (int db = 0; db < 4; ++db)
          oacc[db] = __builtin_amdgcn_mfma_f32_16x16x32_bf16(vf[db][ks], pu.v, oacc[db], 0, 0, 0);
      }
    };

    process(s1v, row_hi, t == ntm1, m1r, o1, l1);
    if (do0) process(s0v, row_lo, t == ip, m0r, o0, l0);
  }

  // epilogue: O[q][d] = oacc/l; lane holds q=lq(+chunk), d = db*16+lg*4+r (4 consecutive)
  {
    float inv0 = 1.0f / l0[0], inv1 = 1.0f / l1[0];
#pragma unroll
    for (int db = 0; db < 4; ++db) {
      ushort4 w0, w1;
      w0.x = f2b(o0[db][0] * inv0); w0.y = f2b(o0[db][1] * inv0);
      w0.z = f2b(o0[db][2] * inv0); w0.w = f2b(o0[db][3] * inv0);
      w1.x = f2b(o1[db][0] * inv1); w1.y = f2b(o1[db][1] * inv1);
      w1.z = f2b(o1[db][2] * inv1); w1.w = f2b(o1[db][3] * inv1);
      *(ushort4*)&Ob[base + (size_t)row_lo * E_DIM + db * 16 + lg * 4] = w0;
      *(ushort4*)&Ob[base + (size_t)row_hi * E_DIM + db * 16 + lg * 4] = w1;
    }
  }
}

extern "C" void kernel_launch(void* const* d_in, const int* in_sizes, int n_in,
                              void* d_out, int out_size, void* d_ws, size_t ws_size,
                              hipStream_t stream) {
  const float* x    = (const float*)d_in[0];
  const float* wq_w = (const float*)d_in[1];
  const float* wq_b = (const float*)d_in[2];
  const float* wk_w = (const float*)d_in[3];
  const float* wk_b = (const float*)d_in[4];
  const float* wv_w = (const float*)d_in[5];
  const float* wv_b = (const float*)d_in[6];
  const float* wo_w = (const float*)d_in[7];
  const float* wo_b = (const float*)d_in[8];
  float* out = (float*)d_out;

  const size_t XE = (size_t)M_ROWS * E_DIM;
  const size_t WE = (size_t)E_DIM * E_DIM;
  char* ws = (char*)d_ws;
  unsigned short* xb    = (unsigned short*)ws; ws += XE * 2;
  unsigned short* wqkvT = (unsigned short*)ws; ws += 3 * WE * 2;  // [3072][1024]
  unsigned short* woT   = (unsigned short*)ws; ws += WE * 2;
  unsigned short* Qb    = (unsigned short*)ws; ws += XE * 2;
  unsigned short* Kb    = (unsigned short*)ws; ws += XE * 2;
  unsigned short* Vt    = (unsigned short*)ws; ws += XE * 2;  // [bh*64+d][s]
  unsigned short* Ao    = (unsigned short*)ws; ws += XE * 2;

  cast_x_kernel<<<2048, 256, 0, stream>>>(x, xb, (int)(XE / 4));
  dim3 tg(E_DIM / 64, E_DIM / 64);
  wtrans_kernel<<<tg, 256, 0, stream>>>(wq_w, wqkvT);
  wtrans_kernel<<<tg, 256, 0, stream>>>(wk_w, wqkvT + WE);
  wtrans_kernel<<<tg, 256, 0, stream>>>(wv_w, wqkvT + 2 * WE);
  wtrans_kernel<<<tg, 256, 0, stream>>>(wo_w, woT);

  gemm_qkv<<<dim3(M_ROWS / 128, 3072 / 128), 256, 0, stream>>>(
      xb, wqkvT, wq_b, wk_b, wv_b, Qb, Kb, Vt);

  attn3_kernel<<<dim3(16, BATCH * N_HEADS), 256, 0, stream>>>(Qb, Kb, Vt, Ao);

  gemm_out<<<dim3(M_ROWS / 128, E_DIM / 128), 256, 0, stream>>>(Ao, woT, wo_b, out);
}